// Round 6
// baseline (164.840 us; speedup 1.0000x reference)
//
#include <hip/hip_runtime.h>
#include <math.h>

// ---------------------------------------------------------------------------
// AsymQuantMatMul: A[4096,2048] fp32, B[2048,4096] fp32 -> out[4096,4096] fp32
// R5: GEMM K-loop restructured to ping-pong double-buffer, BK=64, ONE barrier
//     per iteration. Loads for tile t+1 issue right after the barrier, compute
//     of tile t runs from the other buffer -> each global_load_lds gets a full
//     compute phase to land before its vmcnt drain (vs 0 cyc in the 2-barrier
//     shape). Same 32 KB LDS, same barrier count (32), R1's verified
//     0-conflict swizzle geometry (64B rows, 2-bit XOR).
// ---------------------------------------------------------------------------

#define M_DIM 4096
#define K_DIM 2048
#define N_DIM 4096

using int4v = __attribute__((ext_vector_type(4))) int;

typedef __attribute__((address_space(1))) const void glb_cv;
typedef __attribute__((address_space(3))) void lds_v;

__device__ __forceinline__ int qbyte(float x, float rs, float z) {
    // reference: clip(round(x/scale) + zero, 0, 255), shifted by -128
    float q = fminf(fmaxf(rintf(x * rs) + z, 0.0f), 255.0f);
    return (int)q - 128;
}

__device__ __forceinline__ int sum4(int w) {
    return (int)(signed char)(w) + (int)(signed char)(w >> 8) +
           (int)(signed char)(w >> 16) + (int)(signed char)(w >> 24);
}

// ---- Kernel 1: per-block min/max partials (512 A + 512 B); zero colB ----
__global__ void minmax_stage1(const float* __restrict__ A,
                              const float* __restrict__ B,
                              float* __restrict__ partials,
                              int* __restrict__ colB) {
    int b = blockIdx.x;
    if (b < 16) colB[b * 256 + threadIdx.x] = 0;  // init for quant atomics
    const float* src = (b < 512) ? A : B;
    int lb = (b < 512) ? b : b - 512;
    const float4* v = (const float4*)src + (long)lb * 4096;  // 4096 float4/block
    float mn = INFINITY, mx = -INFINITY;
    for (int i = threadIdx.x; i < 4096; i += 256) {
        float4 x = v[i];
        mn = fminf(mn, fminf(fminf(x.x, x.y), fminf(x.z, x.w)));
        mx = fmaxf(mx, fmaxf(fmaxf(x.x, x.y), fmaxf(x.z, x.w)));
    }
    for (int off = 32; off; off >>= 1) {
        mn = fminf(mn, __shfl_down(mn, off));
        mx = fmaxf(mx, __shfl_down(mx, off));
    }
    __shared__ float smn[4], smx[4];
    int w = threadIdx.x >> 6;
    if ((threadIdx.x & 63) == 0) { smn[w] = mn; smx[w] = mx; }
    __syncthreads();
    if (threadIdx.x == 0) {
        mn = fminf(fminf(smn[0], smn[1]), fminf(smn[2], smn[3]));
        mx = fmaxf(fmaxf(smx[0], smx[1]), fmaxf(smx[2], smx[3]));
        partials[2 * b] = mn;
        partials[2 * b + 1] = mx;
    }
}

// ---- Kernel 2: fused quantize. Blocks 0..2047: A (2 rows each, row-major
// i8, + row sums). Blocks 2048..4095: B 64x64 tile transpose (+ col sums).
// Every block deterministically re-reduces all partials -> identical qp.
__global__ void quant_fused(const float* __restrict__ A,
                            const float* __restrict__ B,
                            const float* __restrict__ partials,
                            signed char* __restrict__ A8,
                            signed char* __restrict__ B8T,
                            int* __restrict__ rowA,
                            int* __restrict__ colB,
                            float* __restrict__ qp) {
    int b = blockIdx.x, t = threadIdx.x;

    // -- reduce all 1024 partial pairs (L2/L3-cached after kernel 1) --
    float mnA = INFINITY, mxA = -INFINITY, mnB = INFINITY, mxB = -INFINITY;
    for (int i = t; i < 512; i += 256) {
        mnA = fminf(mnA, partials[2 * i]);
        mxA = fmaxf(mxA, partials[2 * i + 1]);
        mnB = fminf(mnB, partials[2 * (i + 512)]);
        mxB = fmaxf(mxB, partials[2 * (i + 512) + 1]);
    }
    for (int off = 32; off; off >>= 1) {
        mnA = fminf(mnA, __shfl_down(mnA, off));
        mxA = fmaxf(mxA, __shfl_down(mxA, off));
        mnB = fminf(mnB, __shfl_down(mnB, off));
        mxB = fmaxf(mxB, __shfl_down(mxB, off));
    }
    __shared__ float sred[4][4];
    int w = t >> 6;
    if ((t & 63) == 0) { sred[w][0] = mnA; sred[w][1] = mxA; sred[w][2] = mnB; sred[w][3] = mxB; }
    __syncthreads();
    mnA = fminf(fminf(sred[0][0], sred[1][0]), fminf(sred[2][0], sred[3][0]));
    mxA = fmaxf(fmaxf(sred[0][1], sred[1][1]), fmaxf(sred[2][1], sred[3][1]));
    mnB = fminf(fminf(sred[0][2], sred[1][2]), fminf(sred[2][2], sred[3][2]));
    mxB = fmaxf(fmaxf(sred[0][3], sred[1][3]), fmaxf(sred[2][3], sred[3][3]));
    float sA = (mxA - mnA) / 255.0f;
    float zA = rintf(-mnA / sA);
    float sB = (mxB - mnB) / 255.0f;
    float zB = rintf(-mnB / sB);
    if (b == 0 && t == 0) { qp[0] = sA; qp[1] = zA; qp[2] = sB; qp[3] = zB; }
    __syncthreads();

    if (b < 2048) {
        // ---- A path: 2 rows of 2048, fused row sums ----
        float rs = 1.0f / sA, z = zA;
        long base = (long)b * 4096 + (long)t * 16;
        const float4* v = (const float4*)(A + base);
        union { signed char c[16]; int4 i4; } u;
        int ls = 0;
#pragma unroll
        for (int j = 0; j < 4; j++) {
            float4 x = v[j];
            int q0 = qbyte(x.x, rs, z), q1 = qbyte(x.y, rs, z);
            int q2 = qbyte(x.z, rs, z), q3 = qbyte(x.w, rs, z);
            u.c[j * 4 + 0] = (signed char)q0;
            u.c[j * 4 + 1] = (signed char)q1;
            u.c[j * 4 + 2] = (signed char)q2;
            u.c[j * 4 + 3] = (signed char)q3;
            ls += q0 + q1 + q2 + q3;
        }
        *(int4*)(A8 + base) = u.i4;
        for (int off = 32; off; off >>= 1) ls += __shfl_down(ls, off);
        __shared__ int wsum[4];
        if ((t & 63) == 0) wsum[t >> 6] = ls;
        __syncthreads();
        if (t == 0) rowA[b * 2] = wsum[0] + wsum[1];
        if (t == 128) rowA[b * 2 + 1] = wsum[2] + wsum[3];
    } else {
        // ---- B path: 64x64 tile transpose via int-packed LDS, col sums ----
        float rs = 1.0f / sB, z = zB;
        int bb = b - 2048;
        int k0 = (bb & 31) * 64, n0 = (bb >> 5) * 64;
        __shared__ int tile[64][17];  // [n][k/4], +1 pad
        int cn = (t & 15) * 4;  // n offset within tile
        int kg = (t >> 4) * 4;  // k offset within tile
        int w0 = 0, w1 = 0, w2 = 0, w3 = 0;
#pragma unroll
        for (int r = 0; r < 4; r++) {
            float4 x = *(const float4*)&B[(long)(k0 + kg + r) * N_DIM + n0 + cn];
            w0 |= (qbyte(x.x, rs, z) & 255) << (8 * r);
            w1 |= (qbyte(x.y, rs, z) & 255) << (8 * r);
            w2 |= (qbyte(x.z, rs, z) & 255) << (8 * r);
            w3 |= (qbyte(x.w, rs, z) & 255) << (8 * r);
        }
        int kc = kg >> 2;
        tile[cn + 0][kc] = w0;
        tile[cn + 1][kc] = w1;
        tile[cn + 2][kc] = w2;
        tile[cn + 3][kc] = w3;
        __syncthreads();
        int n2 = t >> 2, kb = (t & 3) * 4;
        int4 v;
        v.x = tile[n2][kb + 0];
        v.y = tile[n2][kb + 1];
        v.z = tile[n2][kb + 2];
        v.w = tile[n2][kb + 3];
        *(int4*)&B8T[(long)(n0 + n2) * K_DIM + k0 + (t & 3) * 16] = v;
        int ls = sum4(v.x) + sum4(v.y) + sum4(v.z) + sum4(v.w);
        ls += __shfl_down(ls, 2);
        ls += __shfl_down(ls, 1);
        if ((t & 3) == 0) atomicAdd(&colB[n0 + n2], ls);
    }
}

// ---- Kernel 3: i8 MFMA GEMM, ping-pong dbuf, BK=64, 1 barrier/iter ----
// 128x128 block, 4 waves each 64x64 (4x4 frags of 16x16x64).
// LDS per buffer: A 128x64 + B 128x64 = 16 KB; two buffers = 32 KB total.
// Swizzle (R1 geometry, measured 0 conflicts): 16B chunk c of row r stored
// at slot c ^ ((r>>1)&3); read koff = (g ^ ((mrow>>1)&3))*16.
// Block->tile: 16 regions of 8x8 tiles keyed to XCD for L2 locality.
#define STAGE(dst_a, dst_b, kk)                                                   \
    do {                                                                          \
        _Pragma("unroll")                                                         \
        for (int jj = 0; jj < 2; jj++) {                                          \
            int ch = t + 256 * jj;                                                \
            __builtin_amdgcn_global_load_lds((glb_cv*)(A8 + aoff[jj] + (kk)),     \
                                             (lds_v*)((dst_a) + ch * 16), 16, 0, 0); \
            __builtin_amdgcn_global_load_lds((glb_cv*)(B8T + boff[jj] + (kk)),    \
                                             (lds_v*)((dst_b) + ch * 16), 16, 0, 0); \
        }                                                                         \
    } while (0)

#define COMPUTE(src_a, src_b)                                                     \
    do {                                                                          \
        int4v af[4], bf[4];                                                       \
        _Pragma("unroll")                                                         \
        for (int i = 0; i < 4; i++)                                               \
            af[i] = *(const int4v*)&(src_a)[(wm + i * 16 + mrow) * 64 + koff];    \
        _Pragma("unroll")                                                         \
        for (int jj = 0; jj < 4; jj++)                                            \
            bf[jj] = *(const int4v*)&(src_b)[(wn + jj * 16 + mrow) * 64 + koff];  \
        _Pragma("unroll")                                                         \
        for (int i = 0; i < 4; i++)                                               \
            _Pragma("unroll")                                                     \
            for (int jj = 0; jj < 4; jj++)                                        \
                acc[i][jj] = __builtin_amdgcn_mfma_i32_16x16x64_i8(af[i], bf[jj], acc[i][jj], 0, 0, 0); \
    } while (0)

__global__ __launch_bounds__(256, 4) void gemm_i8(
        const signed char* __restrict__ A8,
        const signed char* __restrict__ B8T,
        const int* __restrict__ rowA,
        const int* __restrict__ colB,
        const float* __restrict__ qp,
        float* __restrict__ out) {
    __shared__ __align__(16) signed char As0[128 * 64], As1[128 * 64];
    __shared__ __align__(16) signed char Bs0[128 * 64], Bs1[128 * 64];

    // L2-locality block swizzle
    int b = blockIdx.x;
    int xcd = b & 7, i0 = b >> 3;
    int reg = xcd + 8 * (i0 >> 6);    // region 0..15
    int jj0 = i0 & 63;                // 0..63 within region
    int mt = (reg >> 2) * 8 + (jj0 >> 3);
    int nt = (reg & 3) * 8 + (jj0 & 7);
    int r0 = mt * 128, c0 = nt * 128;

    int t = threadIdx.x, lane = t & 63, wave = t >> 6;
    int mrow = lane & 15;
    int g = lane >> 4;               // k-group 0..3
    int wm = (wave >> 1) * 64;       // wave m offset
    int wn = (wave & 1) * 64;        // wave n offset
    int koff = (g ^ ((mrow >> 1) & 3)) * 16;  // swizzled read offset

    int4v acc[4][4];
#pragma unroll
    for (int i = 0; i < 4; i++)
#pragma unroll
        for (int jj = 0; jj < 4; jj++) acc[i][jj] = (int4v){0, 0, 0, 0};

    // Staging offsets: chunk ch -> row=ch>>2, slot p=ch&3 holds global chunk
    // p ^ ((row>>1)&3).
    long aoff[2], boff[2];
#pragma unroll
    for (int jj = 0; jj < 2; jj++) {
        int ch = t + 256 * jj;       // 0..511
        int row = ch >> 2, p = ch & 3;
        int gk = p ^ ((row >> 1) & 3);
        aoff[jj] = (long)(r0 + row) * K_DIM + gk * 16;
        boff[jj] = (long)(c0 + row) * K_DIM + gk * 16;
    }

    // Prologue: stage tile 0 into buffer 0.
    STAGE(As0, Bs0, 0);

    // 32 K-iterations, unrolled x2 for compile-time buffer selection.
    // Barrier semantics per iter: drains vmcnt -> current buffer's loads
    // (issued one full iteration ago) are visible, AND all waves are done
    // reading the buffer we are about to overwrite.
    for (int k0 = 0; k0 < K_DIM; k0 += 128) {
        __syncthreads();
        STAGE(As1, Bs1, k0 + 64);     // prefetch next while computing current
        COMPUTE(As0, Bs0);
        __syncthreads();
        if (k0 + 128 < K_DIM)
            STAGE(As0, Bs0, k0 + 128);
        COMPUTE(As1, Bs1);
    }

    // Epilogue: out = sA*sB*(acc + cB*rowA[m] + cA*colB[n] + K*cA*cB)
    float sA = qp[0], zA = qp[1], sB = qp[2], zB = qp[3];
    int cA = 128 - (int)zA, cB = 128 - (int)zB;
    float ss = sA * sB;
    int Kzz = K_DIM * cA * cB;
    int ocol = c0 + wn + mrow;
    int orow = r0 + wm + g * 4;
#pragma unroll
    for (int i = 0; i < 4; i++) {
        int ra[4];
#pragma unroll
        for (int rr = 0; rr < 4; rr++) ra[rr] = cB * rowA[orow + i * 16 + rr] + Kzz;
#pragma unroll
        for (int jj = 0; jj < 4; jj++) {
            int cc = ocol + jj * 16;
            int can = cA * colB[cc];
#pragma unroll
            for (int rr = 0; rr < 4; rr++) {
                int v = acc[i][jj][rr] + ra[rr] + can;
                __builtin_nontemporal_store(ss * (float)v,
                                            &out[(long)(orow + i * 16 + rr) * N_DIM + cc]);
            }
        }
    }
}

extern "C" void kernel_launch(void* const* d_in, const int* in_sizes, int n_in,
                              void* d_out, int out_size, void* d_ws, size_t ws_size,
                              hipStream_t stream) {
    const float* A = (const float*)d_in[0];
    const float* B = (const float*)d_in[1];
    float* out = (float*)d_out;
    char* ws = (char*)d_ws;

    signed char* A8  = (signed char*)ws;                    //  8 MB
    signed char* B8T = (signed char*)(ws + 8388608);        //  8 MB
    int*   rowA      = (int*)(ws + 16777216);               // 16 KB
    int*   colB      = (int*)(ws + 16793600);               // 16 KB
    float* partials  = (float*)(ws + 16809984);             //  8 KB
    float* qp        = (float*)(ws + 16818176);             // 16 B

    minmax_stage1<<<1024, 256, 0, stream>>>(A, B, partials, colB);
    quant_fused<<<4096, 256, 0, stream>>>(A, B, partials, A8, B8T, rowA, colB, qp);
    gemm_i8<<<1024, 256, 0, stream>>>(A8, B8T, rowA, colB, qp, out);
}